// Round 4
// baseline (3625.298 us; speedup 1.0000x reference)
//
#include <hip/hip_runtime.h>
#include <math.h>

// ---------------- problem constants ----------------
#define B_  16
#define S_  512
#define D_  1024
#define H_  16
#define DH_ 64
#define L_  8
#define FF_ 4096
#define M_  (B_*S_)   // 8192 tokens

typedef __attribute__((ext_vector_type(4))) float  f32x4;
typedef __attribute__((ext_vector_type(8))) short  s8v;
typedef __attribute__((ext_vector_type(4))) short  s4v;
typedef __attribute__((ext_vector_type(8))) __bf16 bf8v;

// f32 -> bf16 bits, round-to-nearest-even
__device__ __forceinline__ short f2bf(float f) {
  union { float f; unsigned u; } x; x.f = f;
  unsigned r = x.u + 0x7fffu + ((x.u >> 16) & 1u);
  return (short)(r >> 16);
}

__device__ __forceinline__ f32x4 mfma16(s8v a, s8v b, f32x4 c) {
  return __builtin_amdgcn_mfma_f32_16x16x32_bf16(
      __builtin_bit_cast(bf8v, a), __builtin_bit_cast(bf8v, b), c, 0, 0, 0);
}

__device__ __forceinline__ float gelu_exact(float v) {
  return 0.5f * v * (1.0f + erff(v * 0.70710678118654752f));
}

// ---------------- weight transpose + f32->bf16 ----------------
// src: [R][C] f32 (one matrix per blockIdx.z, stride R*C), dst: [C][R] bf16
__global__ __launch_bounds__(256) void tcvt(const float* __restrict__ src,
                                            short* __restrict__ dst, int R, int C) {
  __shared__ float tile[32][33];
  const size_t lo = (size_t)blockIdx.z * R * C;
  src += lo; dst += lo;
  const int c0 = blockIdx.x * 32, r0 = blockIdx.y * 32;
  const int tx = threadIdx.x & 31, ty = threadIdx.x >> 5;
#pragma unroll
  for (int i = 0; i < 32; i += 8)
    tile[ty + i][tx] = src[(size_t)(r0 + ty + i) * C + (c0 + tx)];
  __syncthreads();
#pragma unroll
  for (int i = 0; i < 32; i += 8)
    dst[(size_t)(c0 + ty + i) * R + (r0 + tx)] = f2bf(tile[tx][ty + i]);
}

// ---------------- embeddings + LN -> f32 residual (lives in d_out) ----------------
__global__ __launch_bounds__(256) void embed_ln(
    const int* __restrict__ ids, const int* __restrict__ tts,
    const float* __restrict__ tok, const float* __restrict__ pos,
    const float* __restrict__ typ, const float* __restrict__ g,
    const float* __restrict__ bta, float* __restrict__ h) {
  const int row = blockIdx.x;
  const int s = row & (S_ - 1);
  const int id = ids[row], tt = tts[row];
  const int t = threadIdx.x;
  const float4 a = ((const float4*)(tok + (size_t)id * D_))[t];
  const float4 p = ((const float4*)(pos + (size_t)s  * D_))[t];
  const float4 y = ((const float4*)(typ + (size_t)tt * D_))[t];
  float x0 = a.x + p.x + y.x, x1 = a.y + p.y + y.y;
  float x2 = a.z + p.z + y.z, x3 = a.w + p.w + y.w;
  float sum = x0 + x1 + x2 + x3;
  float sq  = x0*x0 + x1*x1 + x2*x2 + x3*x3;
  __shared__ float red[8];
#pragma unroll
  for (int d = 1; d < 64; d <<= 1) { sum += __shfl_xor(sum, d); sq += __shfl_xor(sq, d); }
  if ((t & 63) == 0) { red[t >> 6] = sum; red[(t >> 6) + 4] = sq; }
  __syncthreads();
  sum = red[0] + red[1] + red[2] + red[3];
  sq  = red[4] + red[5] + red[6] + red[7];
  const float mean = sum * (1.f / D_);
  const float var  = sq * (1.f / D_) - mean * mean;
  const float rstd = rsqrtf(fmaxf(var, 0.f) + 1e-12f);
  const float4 gg = ((const float4*)g)[t];
  const float4 bb = ((const float4*)bta)[t];
  float4 o;
  o.x = (x0 - mean) * rstd * gg.x + bb.x;
  o.y = (x1 - mean) * rstd * gg.y + bb.y;
  o.z = (x2 - mean) * rstd * gg.z + bb.z;
  o.w = (x3 - mean) * rstd * gg.w + bb.w;
  ((float4*)(h + (size_t)row * D_))[t] = o;
}

// ---------------- LN(h) -> bf16 activations ----------------
__global__ __launch_bounds__(256) void ln_bf16(
    const float* __restrict__ h, const float* __restrict__ g,
    const float* __restrict__ bta, short* __restrict__ out) {
  const int row = blockIdx.x;
  const int t = threadIdx.x;
  const float4 x = ((const float4*)(h + (size_t)row * D_))[t];
  float sum = x.x + x.y + x.z + x.w;
  float sq  = x.x*x.x + x.y*x.y + x.z*x.z + x.w*x.w;
  __shared__ float red[8];
#pragma unroll
  for (int d = 1; d < 64; d <<= 1) { sum += __shfl_xor(sum, d); sq += __shfl_xor(sq, d); }
  if ((t & 63) == 0) { red[t >> 6] = sum; red[(t >> 6) + 4] = sq; }
  __syncthreads();
  sum = red[0] + red[1] + red[2] + red[3];
  sq  = red[4] + red[5] + red[6] + red[7];
  const float mean = sum * (1.f / D_);
  const float var  = sq * (1.f / D_) - mean * mean;
  const float rstd = rsqrtf(fmaxf(var, 0.f) + 1e-12f);
  const float4 gg = ((const float4*)g)[t];
  const float4 bb = ((const float4*)bta)[t];
  s4v o;
  o[0] = f2bf((x.x - mean) * rstd * gg.x + bb.x);
  o[1] = f2bf((x.y - mean) * rstd * gg.y + bb.y);
  o[2] = f2bf((x.z - mean) * rstd * gg.z + bb.z);
  o[3] = f2bf((x.w - mean) * rstd * gg.w + bb.w);
  *(s4v*)&out[(size_t)row * D_ + t * 4] = o;
}

// ---------------- GEMM: C = A[M,K](bf16) * Bt[N,K]^T (bf16) + bias ----------------
// MODE 0: bf16 out[M][N]   MODE 1: gelu->bf16 out   MODE 2: f32 hres += acc
// MODE 3: bf16 qkv scatter out[B][H][S][DH]
template<int MODE>
__global__ __launch_bounds__(256, 2) void gemm_bt(
    const short* __restrict__ A, const short* __restrict__ Bt,
    const float* __restrict__ bias, short* __restrict__ out,
    float* __restrict__ hres, int N, int K) {
  __shared__ __align__(16) short As[128 * 32];
  __shared__ __align__(16) short Bs[128 * 32];
  const int tid = threadIdx.x;
  const int wid = tid >> 6, lane = tid & 63;
  const int wr = wid >> 1, wc = wid & 1;
  const int l15 = lane & 15, l4 = lane >> 4;

  const short* Ab = A + (size_t)blockIdx.x * 128 * K;
  const short* Bb = Bt + (size_t)blockIdx.y * 128 * K;

  const f32x4 zero4 = {0.f, 0.f, 0.f, 0.f};
  f32x4 acc[4][4];
#pragma unroll
  for (int i = 0; i < 4; ++i)
#pragma unroll
    for (int j = 0; j < 4; ++j) acc[i][j] = zero4;

  const int ldrow = wid * 32 + (lane >> 2);   // +c*16
  const int ldcol = (lane & 3) * 8;           // 0,8,16,24

  s8v ga[2], gb[2];
#pragma unroll
  for (int c = 0; c < 2; ++c) {
    ga[c] = *(const s8v*)(Ab + (size_t)(ldrow + c * 16) * K + ldcol);
    gb[c] = *(const s8v*)(Bb + (size_t)(ldrow + c * 16) * K + ldcol);
  }

  for (int k0 = 0; k0 < K; k0 += 32) {
#pragma unroll
    for (int c = 0; c < 2; ++c) {
      *(s8v*)&As[(ldrow + c * 16) * 32 + ldcol] = ga[c];
      *(s8v*)&Bs[(ldrow + c * 16) * 32 + ldcol] = gb[c];
    }
    __syncthreads();
    if (k0 + 32 < K) {   // prefetch next tile while MFMAs run
#pragma unroll
      for (int c = 0; c < 2; ++c) {
        ga[c] = *(const s8v*)(Ab + (size_t)(ldrow + c * 16) * K + (k0 + 32) + ldcol);
        gb[c] = *(const s8v*)(Bb + (size_t)(ldrow + c * 16) * K + (k0 + 32) + ldcol);
      }
    }
    s8v af[4], bf[4];
#pragma unroll
    for (int mf = 0; mf < 4; ++mf)
      af[mf] = *(const s8v*)&As[(wr * 64 + mf * 16 + l15) * 32 + l4 * 8];
#pragma unroll
    for (int nf = 0; nf < 4; ++nf)
      bf[nf] = *(const s8v*)&Bs[(wc * 64 + nf * 16 + l15) * 32 + l4 * 8];
#pragma unroll
    for (int mf = 0; mf < 4; ++mf)
#pragma unroll
      for (int nf = 0; nf < 4; ++nf)
        acc[mf][nf] = mfma16(af[mf], bf[nf], acc[mf][nf]);
    __syncthreads();
  }

  const int r0 = blockIdx.x * 128 + wr * 64;
  const int c0 = blockIdx.y * 128 + wc * 64;
#pragma unroll
  for (int mf = 0; mf < 4; ++mf) {
#pragma unroll
    for (int nf = 0; nf < 4; ++nf) {
      const int col = c0 + nf * 16 + l15;
      const float bb = bias[col];
#pragma unroll
      for (int r = 0; r < 4; ++r) {
        const int row = r0 + mf * 16 + l4 * 4 + r;
        const float v = acc[mf][nf][r] + bb;
        if (MODE == 0) {
          out[(size_t)row * N + col] = f2bf(v);
        } else if (MODE == 1) {
          out[(size_t)row * N + col] = f2bf(gelu_exact(v));
        } else if (MODE == 2) {
          hres[(size_t)row * N + col] += v;
        } else {
          const int b = row >> 9, s = row & 511, hd = col >> 6, dh = col & 63;
          out[((((size_t)b * H_ + hd) * S_ + s) << 6) + dh] = f2bf(v);
        }
      }
    }
  }
}

// ---------------- flash attention ----------------
// Q,K,V: [B,H,S,DH] bf16.  ctx: [B,S,D] bf16.  scale = 1/8.
__global__ __launch_bounds__(256, 2) void attn(
    const short* __restrict__ Q, const short* __restrict__ K,
    const short* __restrict__ V, short* __restrict__ ctx) {
  __shared__ __align__(16) short Kl[32][72];     // padded rows
  __shared__ __align__(16) short Vt[DH_][40];    // V^T, padded rows
  __shared__ __align__(16) short Pl[4][32 * 40]; // per-wave P

  const int tid = threadIdx.x, wid = tid >> 6, lane = tid & 63;
  const int l15 = lane & 15, l4 = lane >> 4;
  const int bh = blockIdx.y;
  const size_t base = (size_t)bh * S_ * DH_;
  const short* Qb = Q + base;
  const short* Kb = K + base;
  const short* Vb = V + base;

  const int qoff = blockIdx.x * 128 + wid * 32;

  s8v qf[2][2];
#pragma unroll
  for (int mf = 0; mf < 2; ++mf)
#pragma unroll
    for (int ks = 0; ks < 2; ++ks)
      qf[mf][ks] = *(const s8v*)&Qb[(size_t)(qoff + mf * 16 + l15) * DH_ + ks * 32 + l4 * 8];

  const f32x4 zero4 = {0.f, 0.f, 0.f, 0.f};
  f32x4 o[2][4];
  float rm[2][4], rs[2][4];
#pragma unroll
  for (int mf = 0; mf < 2; ++mf) {
#pragma unroll
    for (int nf = 0; nf < 4; ++nf) o[mf][nf] = zero4;
#pragma unroll
    for (int r = 0; r < 4; ++r) { rm[mf][r] = -1e30f; rs[mf][r] = 0.f; }
  }

  const int str = tid >> 3;          // 0..31
  const int stc = (tid & 7) * 8;     // 0..56

  for (int kt = 0; kt < S_ / 32; ++kt) {
    __syncthreads();  // prior iter's LDS reads done before overwrite
    {
      const s8v kk = *(const s8v*)&Kb[(size_t)(kt * 32 + str) * DH_ + stc];
      *(s8v*)&Kl[str][stc] = kk;
      const s8v vv = *(const s8v*)&Vb[(size_t)(kt * 32 + str) * DH_ + stc];
#pragma unroll
      for (int j = 0; j < 8; ++j) Vt[stc + j][str] = vv[j];
    }
    __syncthreads();

    // scores = Q K^T / 8
    f32x4 sc[2][2];
#pragma unroll
    for (int mf = 0; mf < 2; ++mf)
#pragma unroll
      for (int nt = 0; nt < 2; ++nt) sc[mf][nt] = zero4;
#pragma unroll
    for (int nt = 0; nt < 2; ++nt)
#pragma unroll
      for (int ks = 0; ks < 2; ++ks) {
        const s8v kf = *(const s8v*)&Kl[nt * 16 + l15][ks * 32 + l4 * 8];
#pragma unroll
        for (int mf = 0; mf < 2; ++mf)
          sc[mf][nt] = mfma16(qf[mf][ks], kf, sc[mf][nt]);
      }

    // online softmax; frag rows: q=(l>>4)*4+r, cols: key=nt*16+(l&15)
#pragma unroll
    for (int mf = 0; mf < 2; ++mf) {
      float tm[4];
#pragma unroll
      for (int r = 0; r < 4; ++r) {
        sc[mf][0][r] *= 0.125f; sc[mf][1][r] *= 0.125f;
        tm[r] = fmaxf(sc[mf][0][r], sc[mf][1][r]);
      }
#pragma unroll
      for (int d = 1; d < 16; d <<= 1)
#pragma unroll
        for (int r = 0; r < 4; ++r) tm[r] = fmaxf(tm[r], __shfl_xor(tm[r], d));
      float ps[4];
#pragma unroll
      for (int r = 0; r < 4; ++r) {
        const float nm = fmaxf(rm[mf][r], tm[r]);
        const float so = __expf(rm[mf][r] - nm);
        rm[mf][r] = nm;
        rs[mf][r] *= so;
#pragma unroll
        for (int nf = 0; nf < 4; ++nf) o[mf][nf][r] *= so;
        const float p0 = __expf(sc[mf][0][r] - nm);
        const float p1 = __expf(sc[mf][1][r] - nm);
        sc[mf][0][r] = p0; sc[mf][1][r] = p1;
        ps[r] = p0 + p1;
      }
#pragma unroll
      for (int d = 1; d < 16; d <<= 1)
#pragma unroll
        for (int r = 0; r < 4; ++r) ps[r] += __shfl_xor(ps[r], d);
#pragma unroll
      for (int r = 0; r < 4; ++r) rs[mf][r] += ps[r];
#pragma unroll
      for (int nt = 0; nt < 2; ++nt)
#pragma unroll
        for (int r = 0; r < 4; ++r)
          Pl[wid][(mf * 16 + l4 * 4 + r) * 40 + nt * 16 + l15] = f2bf(sc[mf][nt][r]);
    }
    asm volatile("s_waitcnt lgkmcnt(0)" ::: "memory");  // own-wave P writes done

    // PV: o += P * V
    s8v vf[4];
#pragma unroll
    for (int nf = 0; nf < 4; ++nf)
      vf[nf] = *(const s8v*)&Vt[nf * 16 + l15][l4 * 8];
#pragma unroll
    for (int mf = 0; mf < 2; ++mf) {
      const s8v pf = *(const s8v*)&Pl[wid][(mf * 16 + l15) * 40 + l4 * 8];
#pragma unroll
      for (int nf = 0; nf < 4; ++nf)
        o[mf][nf] = mfma16(pf, vf[nf], o[mf][nf]);
    }
  }

  const int bb = bh >> 4, hh = bh & 15;
#pragma unroll
  for (int mf = 0; mf < 2; ++mf)
#pragma unroll
    for (int r = 0; r < 4; ++r) {
      const int qrow = qoff + mf * 16 + l4 * 4 + r;
      const float inv = 1.0f / rs[mf][r];
      short* dst = ctx + (size_t)(bb * S_ + qrow) * D_ + hh * DH_;
#pragma unroll
      for (int nf = 0; nf < 4; ++nf)
        dst[nf * 16 + l15] = f2bf(o[mf][nf][r] * inv);
    }
}

// ---------------- host ----------------
extern "C" void kernel_launch(void* const* d_in, const int* in_sizes, int n_in,
                              void* d_out, int out_size, void* d_ws, size_t ws_size,
                              hipStream_t stream) {
  const int*   ids = (const int*)d_in[0];
  const int*   tts = (const int*)d_in[1];
  const float* tok = (const float*)d_in[2];
  const float* pos = (const float*)d_in[3];
  const float* typ = (const float*)d_in[4];
  const float* eg  = (const float*)d_in[5];
  const float* eb  = (const float*)d_in[6];
  const float* Wq  = (const float*)d_in[7];  const float* bq = (const float*)d_in[8];
  const float* Wk  = (const float*)d_in[9];  const float* bk = (const float*)d_in[10];
  const float* Wv  = (const float*)d_in[11]; const float* bv = (const float*)d_in[12];
  const float* Wo  = (const float*)d_in[13]; const float* bo = (const float*)d_in[14];
  const float* g1  = (const float*)d_in[15]; const float* be1 = (const float*)d_in[16];
  const float* g2  = (const float*)d_in[17]; const float* be2 = (const float*)d_in[18];
  const float* W1  = (const float*)d_in[19]; const float* b1 = (const float*)d_in[20];
  const float* W2  = (const float*)d_in[21]; const float* b2 = (const float*)d_in[22];

  // residual h lives directly in d_out (f32 [M][D] == output shape/dtype)
  float* h = (float*)d_out;

  const size_t szDD  = (size_t)D_ * D_ * 2;
  const size_t szDF  = (size_t)D_ * FF_ * 2;
  const size_t xb_b  = (size_t)M_ * D_ * 2;    // 16 MB
  const size_t big_b = (size_t)M_ * FF_ * 2;   // 64 MB (tb; aliases q/k/v)
  const size_t wfull = (szDD * 4 + szDF * 2) * L_;   // 192 MB
  const bool full = ws_size >= wfull + xb_b + big_b + 8192;

  char* p = (char*)d_ws;
  auto alloc = [&](size_t bytes) { char* r = p; p += (bytes + 255) & ~(size_t)255; return r; };
  const size_t wl = full ? L_ : 1;
  short* wqT = (short*)alloc(szDD * wl);
  short* wkT = (short*)alloc(szDD * wl);
  short* wvT = (short*)alloc(szDD * wl);
  short* woT = (short*)alloc(szDD * wl);
  short* w1T = (short*)alloc(szDF * wl);
  short* w2T = (short*)alloc(szDF * wl);
  short* xb  = (short*)alloc(xb_b);
  char*  big = alloc(big_b);
  short* qb  = (short*)big;
  short* kb  = (short*)(big + xb_b);
  short* vb  = (short*)(big + 2 * xb_b);
  short* cb  = xb;            // ctx aliases xb (dead after QKV GEMMs)
  short* tb  = (short*)big;   // FFN hidden aliases q/k/v (dead after attn)

  if (full) {
    tcvt<<<dim3(D_/32,  D_/32,  L_), 256, 0, stream>>>(Wq, wqT, D_,  D_);
    tcvt<<<dim3(D_/32,  D_/32,  L_), 256, 0, stream>>>(Wk, wkT, D_,  D_);
    tcvt<<<dim3(D_/32,  D_/32,  L_), 256, 0, stream>>>(Wv, wvT, D_,  D_);
    tcvt<<<dim3(D_/32,  D_/32,  L_), 256, 0, stream>>>(Wo, woT, D_,  D_);
    tcvt<<<dim3(FF_/32, D_/32,  L_), 256, 0, stream>>>(W1, w1T, D_,  FF_);
    tcvt<<<dim3(D_/32,  FF_/32, L_), 256, 0, stream>>>(W2, w2T, FF_, D_);
  }

  embed_ln<<<M_, 256, 0, stream>>>(ids, tts, tok, pos, typ, eg, eb, h);

  for (int l = 0; l < L_; ++l) {
    if (!full) {
      tcvt<<<dim3(D_/32,  D_/32,  1), 256, 0, stream>>>(Wq + (size_t)l*D_*D_,  wqT, D_,  D_);
      tcvt<<<dim3(D_/32,  D_/32,  1), 256, 0, stream>>>(Wk + (size_t)l*D_*D_,  wkT, D_,  D_);
      tcvt<<<dim3(D_/32,  D_/32,  1), 256, 0, stream>>>(Wv + (size_t)l*D_*D_,  wvT, D_,  D_);
      tcvt<<<dim3(D_/32,  D_/32,  1), 256, 0, stream>>>(Wo + (size_t)l*D_*D_,  woT, D_,  D_);
      tcvt<<<dim3(FF_/32, D_/32,  1), 256, 0, stream>>>(W1 + (size_t)l*D_*FF_, w1T, D_,  FF_);
      tcvt<<<dim3(D_/32,  FF_/32, 1), 256, 0, stream>>>(W2 + (size_t)l*D_*FF_, w2T, FF_, D_);
    }
    const size_t od = full ? (size_t)l * D_ * D_  : 0;
    const size_t of = full ? (size_t)l * D_ * FF_ : 0;

    ln_bf16<<<M_, 256, 0, stream>>>(h, g1 + l*D_, be1 + l*D_, xb);
    gemm_bt<3><<<dim3(M_/128, D_/128), 256, 0, stream>>>(xb, wqT + od, bq + l*D_, qb, nullptr, D_, D_);
    gemm_bt<3><<<dim3(M_/128, D_/128), 256, 0, stream>>>(xb, wkT + od, bk + l*D_, kb, nullptr, D_, D_);
    gemm_bt<3><<<dim3(M_/128, D_/128), 256, 0, stream>>>(xb, wvT + od, bv + l*D_, vb, nullptr, D_, D_);
    attn<<<dim3(S_/128, B_*H_), 256, 0, stream>>>(qb, kb, vb, cb);
    gemm_bt<2><<<dim3(M_/128, D_/128), 256, 0, stream>>>(cb, woT + od, bo + l*D_, nullptr, h, D_, D_);
    ln_bf16<<<M_, 256, 0, stream>>>(h, g2 + l*D_, be2 + l*D_, xb);
    gemm_bt<1><<<dim3(M_/128, FF_/128), 256, 0, stream>>>(xb, w1T + of, b1 + l*FF_, tb, nullptr, FF_, D_);
    gemm_bt<2><<<dim3(M_/128, D_/128), 256, 0, stream>>>(tb, w2T + of, b2 + l*D_, nullptr, h, D_, FF_);
  }
}